// Round 2
// baseline (15567.256 us; speedup 1.0000x reference)
//
#include <hip/hip_runtime.h>
#include <hip/hip_bf16.h>
#include <hip/hip_fp16.h>

typedef _Float16 v2h __attribute__((ext_vector_type(2)));

__device__ __forceinline__ float fdot2u(unsigned int a, unsigned int b, float c){
  return __builtin_amdgcn_fdot2(__builtin_bit_cast(v2h, a), __builtin_bit_cast(v2h, b), c, false);
}
__device__ __forceinline__ unsigned int packh2(float a, float b){
  union{ _Float16 h[2]; unsigned int u; } z;
  z.h[0] = (_Float16)a; z.h[1] = (_Float16)b; return z.u;
}
__device__ __forceinline__ float h2f(unsigned short s){
  return (float)__builtin_bit_cast(_Float16, s);
}
__device__ __forceinline__ float sigf(float x){
  return __builtin_amdgcn_rcpf(1.0f + __builtin_amdgcn_exp2f(-1.44269504f*x));
}
__device__ __forceinline__ float tanhf_(float x){
  return 2.0f*__builtin_amdgcn_rcpf(1.0f + __builtin_amdgcn_exp2f(-2.88539008f*x)) - 1.0f;
}

// ---------------- Kernel A: weight conversion / bias fuse ----------------
__global__ void prep_kernel(const float* __restrict__ Whh, const float* __restrict__ Wfc,
                            const float* __restrict__ bih, const float* __restrict__ bhh,
                            unsigned int* __restrict__ whh16, unsigned int* __restrict__ wfc16,
                            float* __restrict__ bsum){
  int i = blockIdx.x*256 + threadIdx.x;
  if (i < 131072){                       // W_hh (1024 x 256) -> f16 pair dwords (1024 x 128)
    int r = i >> 7, d = i & 127;
    whh16[i] = packh2(Whh[r*256 + 2*d], Whh[r*256 + 2*d + 1]);
  } else if (i < 139264){                // W_fc (64 x 256) -> (64 x 128)
    int j = i - 131072; int o = j >> 7, d = j & 127;
    wfc16[j] = packh2(Wfc[o*256 + 2*d], Wfc[o*256 + 2*d + 1]);
  } else if (i < 140288){                // bsum = b_ih + b_hh
    int g = i - 139264;
    bsum[g] = bih[g] + bhh[g];
  }
}

// ---------------- Kernel B: x_proj = x @ W_ih^T + bsum (f16 out) ----------------
#define XS 68
__global__ __launch_bounds__(256) void xproj_kernel(const float* __restrict__ x,
                          const float* __restrict__ Wih,
                          const float* __restrict__ bsum, unsigned int* __restrict__ xproj){
  __shared__ unsigned int lx[128*XS];
  __shared__ unsigned int lw[64*XS];
  __shared__ float lb[64];
  int t  = threadIdx.x;
  int bt0 = blockIdx.x*128, g0 = blockIdx.y*64;
  int rr = t >> 4, cc = t & 15;
  #pragma unroll
  for (int it=0; it<8; ++it){            // stage x tile (128 rows x 128 f32 -> f16 pairs)
    int row = rr + it*16;
    const float4* s = (const float4*)(x + (size_t)(bt0+row)*128 + cc*8);
    float4 a = s[0], b = s[1];
    uint4 w; w.x=packh2(a.x,a.y); w.y=packh2(a.z,a.w); w.z=packh2(b.x,b.y); w.w=packh2(b.z,b.w);
    *(uint4*)&lx[row*XS + cc*4] = w;
  }
  #pragma unroll
  for (int it=0; it<4; ++it){            // stage W tile (64 rows)
    int row = rr + it*16;
    const float4* s = (const float4*)(Wih + (size_t)(g0+row)*128 + cc*8);
    float4 a = s[0], b = s[1];
    uint4 w; w.x=packh2(a.x,a.y); w.y=packh2(a.z,a.w); w.z=packh2(b.x,b.y); w.w=packh2(b.z,b.w);
    *(uint4*)&lw[row*XS + cc*4] = w;
  }
  if (t < 64) lb[t] = bsum[g0 + t];
  __syncthreads();

  float acc[8][4];
  #pragma unroll
  for (int j=0;j<8;++j)
    #pragma unroll
    for (int i=0;i<4;++i) acc[j][i]=0.f;

  #pragma unroll
  for (int d4=0; d4<16; ++d4){
    uint4 wv[4], xv[8];
    #pragma unroll
    for (int i=0;i<4;++i) wv[i] = *(const uint4*)&lw[(cc*4+i)*XS + d4*4];
    #pragma unroll
    for (int j=0;j<8;++j) xv[j] = *(const uint4*)&lx[(rr*8+j)*XS + d4*4];
    #pragma unroll
    for (int j=0;j<8;++j){
      #pragma unroll
      for (int i=0;i<4;++i){
        float a = acc[j][i];
        a = fdot2u(xv[j].x, wv[i].x, a);
        a = fdot2u(xv[j].y, wv[i].y, a);
        a = fdot2u(xv[j].z, wv[i].z, a);
        a = fdot2u(xv[j].w, wv[i].w, a);
        acc[j][i] = a;
      }
    }
  }
  #pragma unroll
  for (int j=0;j<8;++j){
    int bt = bt0 + rr*8 + j;
    uint2 o2;
    o2.x = packh2(acc[j][0]+lb[cc*4+0], acc[j][1]+lb[cc*4+1]);
    o2.y = packh2(acc[j][2]+lb[cc*4+2], acc[j][3]+lb[cc*4+3]);
    *(uint2*)&xproj[(size_t)bt*512 + (g0>>1) + cc*2] = o2;
  }
}

// ---------------- Kernel C: recurrent LSTM ----------------
// 512 threads/WG, 1 WG per batch. Thread t: unit u=t>>1, p=t&1.
//   p=0 owns gate-rows {i: u, g: 512+u}; p=1 owns {f: 256+u, o: 768+u}.
// Weights: 26 uint4/row in VGPR (k-dwords 0..103), 6 uint4/row in LDS
//   (k-dwords 104..127), stored [chunk][thread] so lanes read consecutive
//   16B -> conflict-free ds_read_b128. h double-buffered in LDS, read as
//   wave-uniform b128 (broadcast). One barrier per step.
#define WR4 26                 // uint4 per row in registers
#define WL4 6                  // uint4 per row in LDS
#define NLW (12*512)           // total LDS weight uint4 (2 rows x 6 x 512 thr)
#define HOFF (NLW*4)           // dword offset of h double-buffer

extern "C" __global__ void __launch_bounds__(512,2) lstm_kernel(
    const unsigned int* __restrict__ xproj, const unsigned int* __restrict__ whh16,
    unsigned short* __restrict__ h_all)
{
  extern __shared__ unsigned int lds[];
  uint4* lw4 = (uint4*)lds;
  const int t = threadIdx.x;
  const int u = t >> 1, p = t & 1;
  const int b = blockIdx.x;
  const int R0 = p*256 + u;          // i (p=0) or f (p=1)
  const int R1 = R0 + 512;           // g (p=0) or o (p=1)

  uint4 w0[WR4], w1[WR4];
  {
    const uint4* s0 = (const uint4*)(whh16) + (size_t)R0*32;
    const uint4* s1 = (const uint4*)(whh16) + (size_t)R1*32;
    #pragma unroll
    for (int d=0; d<WR4; ++d){ w0[d] = s0[d]; w1[d] = s1[d]; }
    #pragma unroll
    for (int q=0; q<WL4; ++q){
      lw4[q*512 + t]          = s0[WR4 + q];
      lw4[(WL4+q)*512 + t]    = s1[WR4 + q];
    }
  }
  if (t < 256) lds[HOFF + t] = 0u;   // zero both h buffers (step 0 reads zeros)

  const unsigned short* xpb = (const unsigned short*)xproj + (size_t)b*2048*1024;
  unsigned short xn0 = xpb[R0], xn1 = xpb[R1];
  float c = 0.f;
  unsigned short* hout = h_all + (size_t)b*2048*256 + u;
  __syncthreads();

  for (int tt=0; tt<2048; ++tt){
    const int cur = tt & 1;
    float A0 = h2f(xn0), B0 = h2f(xn1);   // accumulators (x_proj pre-acts)
    float A1 = 0.f, B1 = 0.f;             // second partials (halve dep chain)

    // prefetch next step's x_proj
    int tn = (tt+1 < 2048) ? tt+1 : 2047;
    xn0 = xpb[(size_t)tn*1024 + R0];
    xn1 = xpb[(size_t)tn*1024 + R1];

    const unsigned int* hb = lds + HOFF + cur*128;
    #pragma unroll
    for (int d=0; d<WR4; ++d){
      uint4 h4 = *(const uint4*)(hb + d*4);
      A0 = fdot2u(w0[d].x, h4.x, A0); A1 = fdot2u(w0[d].y, h4.y, A1);
      A0 = fdot2u(w0[d].z, h4.z, A0); A1 = fdot2u(w0[d].w, h4.w, A1);
      B0 = fdot2u(w1[d].x, h4.x, B0); B1 = fdot2u(w1[d].y, h4.y, B1);
      B0 = fdot2u(w1[d].z, h4.z, B0); B1 = fdot2u(w1[d].w, h4.w, B1);
    }
    #pragma unroll
    for (int q=0; q<WL4; ++q){
      uint4 h4 = *(const uint4*)(hb + (WR4+q)*4);
      uint4 wa = lw4[q*512 + t];
      uint4 wb = lw4[(WL4+q)*512 + t];
      A0 = fdot2u(wa.x, h4.x, A0); A1 = fdot2u(wa.y, h4.y, A1);
      A0 = fdot2u(wa.z, h4.z, A0); A1 = fdot2u(wa.w, h4.w, A1);
      B0 = fdot2u(wb.x, h4.x, B0); B1 = fdot2u(wb.y, h4.y, B1);
      B0 = fdot2u(wb.z, h4.z, B0); B1 = fdot2u(wb.w, h4.w, B1);
    }
    float a0 = A0 + A1;                   // pre-act of R0 (i or f)
    float a1 = B0 + B1;                   // pre-act of R1 (g or o)

    // activate own gates, then exchange within the lane pair
    float v0 = sigf(a0);                              // i (p=0) or f (p=1)
    float v1 = p ? sigf(a1) : tanhf_(a1);             // g (p=0) or o (p=1)
    float o0 = __shfl_xor(v0, 1);
    float o1 = __shfl_xor(v1, 1);
    float gi = p ? o0 : v0;
    float gf = p ? v0 : o0;
    float gg = p ? o1 : v1;
    float go = p ? v1 : o1;
    c = gf*c + gi*gg;
    float h = go * tanhf_(c);
    unsigned short hh = __builtin_bit_cast(unsigned short, (_Float16)h);
    if (p == 0){
      ((unsigned short*)(lds + HOFF + (cur^1)*128))[u] = hh;  // next step's h
      hout[(size_t)tt*256] = hh;                              // h_all for fc
    }
    __syncthreads();
  }
}

// ---------------- Kernel D: logits = h @ W_fc^T + b_fc ; softmax over O=64 ----------------
__global__ __launch_bounds__(1024) void fc_softmax_kernel(const unsigned short* __restrict__ h_all,
      const unsigned int* __restrict__ wfc16, const float* __restrict__ bfc,
      float* __restrict__ out){
  __shared__ unsigned int lwf[64*132];
  __shared__ unsigned int lh[16*132];
  int t = threadIdx.x;
  int bt0 = blockIdx.x*16;
  {
    const uint4* s = (const uint4*)(wfc16 + (size_t)t*8);
    uint4 a = s[0], b = s[1];
    unsigned int* dst = &lwf[(t>>4)*132 + (t&15)*8];
    *(uint4*)dst = a; *(uint4*)(dst+4) = b;
  }
  {
    int row = t>>6, col = (t&63)*2;
    const unsigned int* hsrc = (const unsigned int*)h_all;
    uint2 v = *(const uint2*)(hsrc + (size_t)(bt0+row)*128 + col);
    *(uint2*)&lh[row*132 + col] = v;
  }
  __syncthreads();
  int w = t>>6, o = t&63;
  int bt = bt0 + w;
  float acc = bfc[o];
  #pragma unroll
  for (int d4=0; d4<32; ++d4){
    uint4 hq = *(const uint4*)&lh[w*132 + d4*4];
    uint4 wq = *(const uint4*)&lwf[o*132 + d4*4];
    acc = fdot2u(wq.x, hq.x, acc);
    acc = fdot2u(wq.y, hq.y, acc);
    acc = fdot2u(wq.z, hq.z, acc);
    acc = fdot2u(wq.w, hq.w, acc);
  }
  float m = acc;
  #pragma unroll
  for (int off=32; off>=1; off>>=1) m = fmaxf(m, __shfl_xor(m, off));
  float e = __builtin_amdgcn_exp2f(1.44269504f*(acc - m));
  float s = e;
  #pragma unroll
  for (int off=32; off>=1; off>>=1) s += __shfl_xor(s, off);
  out[(size_t)bt*64 + o] = e * __builtin_amdgcn_rcpf(s);
}

// ---------------- launch ----------------
extern "C" void kernel_launch(void* const* d_in, const int* in_sizes, int n_in,
                              void* d_out, int out_size, void* d_ws, size_t ws_size,
                              hipStream_t stream){
  const float* x   = (const float*)d_in[0];
  const float* Wih = (const float*)d_in[1];
  const float* Whh = (const float*)d_in[2];
  const float* bih = (const float*)d_in[3];
  const float* bhh = (const float*)d_in[4];
  const float* Wfc = (const float*)d_in[5];
  const float* bfc = (const float*)d_in[6];
  float* out = (float*)d_out;

  char* ws = (char*)d_ws;
  unsigned int*   xproj = (unsigned int*)ws;                         // 128 MB (f16 pairs)
  unsigned short* h_all = (unsigned short*)(ws + 134217728);         // 32 MB (f16)
  unsigned int*   whh16 = (unsigned int*)(ws + 134217728 + 33554432);// 512 KB
  unsigned int*   wfc16 = whh16 + 131072;                            // 32 KB
  float*          bsum  = (float*)(wfc16 + 8192);                    // 4 KB

  prep_kernel<<<548, 256, 0, stream>>>(Whh, Wfc, bih, bhh, whh16, wfc16, bsum);
  dim3 gb(512, 16);
  xproj_kernel<<<gb, 256, 0, stream>>>(x, Wih, bsum, xproj);
  int dyn = (HOFF + 256) * 4;   // 99,328 B dynamic LDS
  hipFuncSetAttribute((const void*)lstm_kernel, hipFuncAttributeMaxDynamicSharedMemorySize, dyn);
  lstm_kernel<<<32, 512, dyn, stream>>>(xproj, whh16, h_all);
  fc_softmax_kernel<<<4096, 1024, 0, stream>>>(h_all, wfc16, bfc, out);
}

// Round 3
// 3457.020 us; speedup vs baseline: 4.5031x; 4.5031x over previous
//
#include <hip/hip_runtime.h>
#include <hip/hip_bf16.h>
#include <hip/hip_fp16.h>

typedef _Float16 v2h __attribute__((ext_vector_type(2)));

__device__ __forceinline__ float fdot2u(unsigned int a, unsigned int b, float c){
  return __builtin_amdgcn_fdot2(__builtin_bit_cast(v2h, a), __builtin_bit_cast(v2h, b), c, false);
}
__device__ __forceinline__ unsigned int packh2(float a, float b){
  union{ _Float16 h[2]; unsigned int u; } z;
  z.h[0] = (_Float16)a; z.h[1] = (_Float16)b; return z.u;
}
__device__ __forceinline__ float h2f(unsigned short s){
  return (float)__builtin_bit_cast(_Float16, s);
}
__device__ __forceinline__ float sigf(float x){
  return __builtin_amdgcn_rcpf(1.0f + __builtin_amdgcn_exp2f(-1.44269504f*x));
}
__device__ __forceinline__ float tanhf_(float x){
  return 2.0f*__builtin_amdgcn_rcpf(1.0f + __builtin_amdgcn_exp2f(-2.88539008f*x)) - 1.0f;
}

// ---------------- Kernel A: weight conversion (TRANSPOSED chunks) ----------------
// whhT layout (dwords): [q=0..31][row=0..1023][l=0..3]  (q*4096 + row*4 + l)
// so uint4 index = q*1024 + row  -> lstm loads are lane-coalesced.
__global__ void prep_kernel(const float* __restrict__ Whh, const float* __restrict__ Wfc,
                            const float* __restrict__ bih, const float* __restrict__ bhh,
                            unsigned int* __restrict__ whhT, unsigned int* __restrict__ wfc16,
                            float* __restrict__ bsum){
  int i = blockIdx.x*256 + threadIdx.x;
  if (i < 131072){                       // W_hh (1024 x 256) f32 -> f16 pair dwords
    int r = i >> 7, d = i & 127;
    int q = d >> 2, l = d & 3;
    whhT[q*4096 + r*4 + l] = packh2(Whh[r*256 + 2*d], Whh[r*256 + 2*d + 1]);
  } else if (i < 139264){                // W_fc (64 x 256) -> (64 x 128)
    int j = i - 131072; int o = j >> 7, d = j & 127;
    wfc16[j] = packh2(Wfc[o*256 + 2*d], Wfc[o*256 + 2*d + 1]);
  } else if (i < 140288){                // bsum = b_ih + b_hh
    int g = i - 139264;
    bsum[g] = bih[g] + bhh[g];
  }
}

// ---------------- Kernel B: x_proj = x @ W_ih^T + bsum (f16 out) ----------------
#define XS 68
__global__ __launch_bounds__(256) void xproj_kernel(const float* __restrict__ x,
                          const float* __restrict__ Wih,
                          const float* __restrict__ bsum, unsigned int* __restrict__ xproj){
  __shared__ unsigned int lx[128*XS];
  __shared__ unsigned int lw[64*XS];
  __shared__ float lb[64];
  int t  = threadIdx.x;
  int bt0 = blockIdx.x*128, g0 = blockIdx.y*64;
  int rr = t >> 4, cc = t & 15;
  #pragma unroll
  for (int it=0; it<8; ++it){
    int row = rr + it*16;
    const float4* s = (const float4*)(x + (size_t)(bt0+row)*128 + cc*8);
    float4 a = s[0], b = s[1];
    uint4 w; w.x=packh2(a.x,a.y); w.y=packh2(a.z,a.w); w.z=packh2(b.x,b.y); w.w=packh2(b.z,b.w);
    *(uint4*)&lx[row*XS + cc*4] = w;
  }
  #pragma unroll
  for (int it=0; it<4; ++it){
    int row = rr + it*16;
    const float4* s = (const float4*)(Wih + (size_t)(g0+row)*128 + cc*8);
    float4 a = s[0], b = s[1];
    uint4 w; w.x=packh2(a.x,a.y); w.y=packh2(a.z,a.w); w.z=packh2(b.x,b.y); w.w=packh2(b.z,b.w);
    *(uint4*)&lw[row*XS + cc*4] = w;
  }
  if (t < 64) lb[t] = bsum[g0 + t];
  __syncthreads();

  float acc[8][4];
  #pragma unroll
  for (int j=0;j<8;++j)
    #pragma unroll
    for (int i=0;i<4;++i) acc[j][i]=0.f;

  #pragma unroll
  for (int d4=0; d4<16; ++d4){
    uint4 wv[4], xv[8];
    #pragma unroll
    for (int i=0;i<4;++i) wv[i] = *(const uint4*)&lw[(cc*4+i)*XS + d4*4];
    #pragma unroll
    for (int j=0;j<8;++j) xv[j] = *(const uint4*)&lx[(rr*8+j)*XS + d4*4];
    #pragma unroll
    for (int j=0;j<8;++j){
      #pragma unroll
      for (int i=0;i<4;++i){
        float a = acc[j][i];
        a = fdot2u(xv[j].x, wv[i].x, a);
        a = fdot2u(xv[j].y, wv[i].y, a);
        a = fdot2u(xv[j].z, wv[i].z, a);
        a = fdot2u(xv[j].w, wv[i].w, a);
        acc[j][i] = a;
      }
    }
  }
  #pragma unroll
  for (int j=0;j<8;++j){
    int bt = bt0 + rr*8 + j;
    uint2 o2;
    o2.x = packh2(acc[j][0]+lb[cc*4+0], acc[j][1]+lb[cc*4+1]);
    o2.y = packh2(acc[j][2]+lb[cc*4+2], acc[j][3]+lb[cc*4+3]);
    *(uint2*)&xproj[(size_t)bt*512 + (g0>>1) + cc*2] = o2;
  }
}

// ---------------- Kernel C: recurrent LSTM ----------------
// 1024 threads/WG (16 waves, 4/SIMD -> 128 unified regs/wave), 1 WG/batch.
// Thread t owns gate-row t: gate g=t>>8 (wave-uniform), unit u=t&255.
// Weights: 24 uint4 in VGPR + 8 uint4 in LDS ([chunk][thread] -> conflict-free
// b128). h double-buffered in LDS (wave-uniform b128 broadcast reads).
// Gate exchange via LDS [g][u] (conflict-free). 2 barriers/step.
#define WR4 24                   // uint4 weight chunks in registers
#define WL4 8                    // uint4 weight chunks in LDS
#define HOFF (WL4*4096)          // dword offset of h double-buffer (2 x 128 dwords)
#define GOFF (HOFF + 256)        // dword offset of gate-exchange buffer (1024 f32)

extern "C" __global__ void __launch_bounds__(1024,4) lstm_kernel(
    const unsigned int* __restrict__ whhT, const unsigned int* __restrict__ xproj,
    unsigned short* __restrict__ h_all)
{
  extern __shared__ unsigned int lds[];
  uint4* lw4 = (uint4*)lds;
  float* gbuf = (float*)(lds + GOFF);
  const int t = threadIdx.x;
  const int g = t >> 8, u = t & 255;
  const int b = blockIdx.x;

  const uint4* wsrc = (const uint4*)whhT;
  uint4 w4[WR4];
  #pragma unroll
  for (int d=0; d<WR4; ++d) w4[d] = wsrc[d*1024 + t];
  #pragma unroll
  for (int q=0; q<WL4; ++q) lw4[q*1024 + t] = wsrc[(WR4+q)*1024 + t];
  if (t < 128) lds[HOFF + t] = 0u;   // h buffer 0 = zeros for step 0

  const unsigned short* xpb = (const unsigned short*)xproj + (size_t)b*2048*1024;
  unsigned short xn = xpb[t];
  float c = 0.f;
  unsigned short* hout = h_all + (size_t)b*2048*256 + u;
  __syncthreads();

  for (int tt=0; tt<2048; ++tt){
    const int cur = tt & 1;
    float A0 = h2f(xn), A1 = 0.f;

    // prefetch next step's x_proj pre-activation for this row
    int tn = (tt+1 < 2048) ? tt+1 : 2047;
    xn = xpb[(size_t)tn*1024 + t];

    const unsigned int* hb = lds + HOFF + cur*128;
    #pragma unroll
    for (int d=0; d<WR4; ++d){
      uint4 h4 = *(const uint4*)(hb + d*4);
      A0 = fdot2u(w4[d].x, h4.x, A0); A1 = fdot2u(w4[d].y, h4.y, A1);
      A0 = fdot2u(w4[d].z, h4.z, A0); A1 = fdot2u(w4[d].w, h4.w, A1);
    }
    #pragma unroll
    for (int q=0; q<WL4; ++q){
      uint4 wl = lw4[q*1024 + t];
      uint4 h4 = *(const uint4*)(hb + (WR4+q)*4);
      A0 = fdot2u(wl.x, h4.x, A0); A1 = fdot2u(wl.y, h4.y, A1);
      A0 = fdot2u(wl.z, h4.z, A0); A1 = fdot2u(wl.w, h4.w, A1);
    }
    float a = A0 + A1;
    // activate own gate (g is wave-uniform: no divergence)
    float v = (g == 2) ? tanhf_(a) : sigf(a);
    gbuf[g*256 + u] = v;
    __syncthreads();

    float gi = gbuf[u];
    float gf = gbuf[256 + u];
    float gg = gbuf[512 + u];
    float go = gbuf[768 + u];
    c = gf*c + gi*gg;
    float h = go * tanhf_(c);
    unsigned short hh = __builtin_bit_cast(unsigned short, (_Float16)h);
    if (g == 0){
      ((unsigned short*)(lds + HOFF + (cur^1)*128))[u] = hh;  // next step's h
      hout[(size_t)tt*256] = hh;                              // h_all for fc
    }
    __syncthreads();
  }
}

// ---------------- Kernel D: logits = h @ W_fc^T + b_fc ; softmax over O=64 ----------------
__global__ __launch_bounds__(1024) void fc_softmax_kernel(const unsigned short* __restrict__ h_all,
      const unsigned int* __restrict__ wfc16, const float* __restrict__ bfc,
      float* __restrict__ out){
  __shared__ unsigned int lwf[64*132];
  __shared__ unsigned int lh[16*132];
  int t = threadIdx.x;
  int bt0 = blockIdx.x*16;
  {
    const uint4* s = (const uint4*)(wfc16 + (size_t)t*8);
    uint4 a = s[0], b = s[1];
    unsigned int* dst = &lwf[(t>>4)*132 + (t&15)*8];
    *(uint4*)dst = a; *(uint4*)(dst+4) = b;
  }
  {
    int row = t>>6, col = (t&63)*2;
    const unsigned int* hsrc = (const unsigned int*)h_all;
    uint2 v = *(const uint2*)(hsrc + (size_t)(bt0+row)*128 + col);
    *(uint2*)&lh[row*132 + col] = v;
  }
  __syncthreads();
  int w = t>>6, o = t&63;
  int bt = bt0 + w;
  float acc = bfc[o];
  #pragma unroll
  for (int d4=0; d4<32; ++d4){
    uint4 hq = *(const uint4*)&lh[w*132 + d4*4];
    uint4 wq = *(const uint4*)&lwf[o*132 + d4*4];
    acc = fdot2u(wq.x, hq.x, acc);
    acc = fdot2u(wq.y, hq.y, acc);
    acc = fdot2u(wq.z, hq.z, acc);
    acc = fdot2u(wq.w, hq.w, acc);
  }
  float m = acc;
  #pragma unroll
  for (int off=32; off>=1; off>>=1) m = fmaxf(m, __shfl_xor(m, off));
  float e = __builtin_amdgcn_exp2f(1.44269504f*(acc - m));
  float s = e;
  #pragma unroll
  for (int off=32; off>=1; off>>=1) s += __shfl_xor(s, off);
  out[(size_t)bt*64 + o] = e * __builtin_amdgcn_rcpf(s);
}

// ---------------- launch ----------------
extern "C" void kernel_launch(void* const* d_in, const int* in_sizes, int n_in,
                              void* d_out, int out_size, void* d_ws, size_t ws_size,
                              hipStream_t stream){
  const float* x   = (const float*)d_in[0];
  const float* Wih = (const float*)d_in[1];
  const float* Whh = (const float*)d_in[2];
  const float* bih = (const float*)d_in[3];
  const float* bhh = (const float*)d_in[4];
  const float* Wfc = (const float*)d_in[5];
  const float* bfc = (const float*)d_in[6];
  float* out = (float*)d_out;

  char* ws = (char*)d_ws;
  unsigned int*   xproj = (unsigned int*)ws;                         // 128 MB (f16 pairs)
  unsigned short* h_all = (unsigned short*)(ws + 134217728);         // 32 MB (f16)
  unsigned int*   whhT  = (unsigned int*)(ws + 134217728 + 33554432);// 512 KB (transposed)
  unsigned int*   wfc16 = whhT + 131072;                             // 32 KB
  float*          bsum  = (float*)(wfc16 + 8192);                    // 4 KB

  prep_kernel<<<548, 256, 0, stream>>>(Whh, Wfc, bih, bhh, whhT, wfc16, bsum);
  dim3 gb(512, 16);
  xproj_kernel<<<gb, 256, 0, stream>>>(x, Wih, bsum, xproj);
  int dyn = (GOFF + 1024) * 4;   // 136,192 B dynamic LDS
  hipFuncSetAttribute((const void*)lstm_kernel, hipFuncAttributeMaxDynamicSharedMemorySize, dyn);
  lstm_kernel<<<32, 1024, dyn, stream>>>(whhT, xproj, h_all);
  fc_softmax_kernel<<<4096, 1024, 0, stream>>>(h_all, wfc16, bfc, out);
}